// Round 9
// baseline (11912.225 us; speedup 1.0000x reference)
//
#include <hip/hip_runtime.h>

#define BSZ 64
#define NN 44
#define NODES (BSZ*NN)      /* 2816 */
#define HDIM 256

__device__ __forceinline__ float silu_f(float v){ return v / (1.0f + __expf(-v)); }

// ---------------- rproj[b][c] = rep[b]@W_rep[:,c] + b_rep[c]
__global__ __launch_bounds__(256)
void repproj_kernel(const float* __restrict__ rep, const float* __restrict__ W_rep,
                    const float* __restrict__ b_rep, float* __restrict__ out) {
  int b = blockIdx.x, c = threadIdx.x;
  float acc = b_rep[c];
  const float* r = rep + (size_t)b * 512;
  for (int k = 0; k < 512; k++) acc += r[k] * W_rep[(size_t)k * 256 + c];
  out[(size_t)b * 256 + c] = acc;
}

// ---------------- embedding: h = (xh[:,3:9]*nm, t) @ W_embed + b_embed + rproj
__global__ __launch_bounds__(256)
void embed_kernel(const float* __restrict__ xh, const float* __restrict__ t,
                  const float* __restrict__ nmask,
                  const float* __restrict__ W_embed, const float* __restrict__ b_embed,
                  const float* __restrict__ repproj,
                  float* __restrict__ h, float* __restrict__ x0, float* __restrict__ x) {
  int m = blockIdx.x;
  int b = m / NN;
  int c = threadIdx.x;
  float nm = nmask[m];
  float acc = b_embed[c] + repproj[(size_t)b * 256 + c];
  for (int kk = 0; kk < 6; kk++)
    acc += xh[(size_t)m * 9 + 3 + kk] * nm * W_embed[(size_t)kk * 256 + c];
  acc += t[b] * W_embed[6 * 256 + c];
  h[(size_t)m * 256 + c] = acc;
  if (c < 3) {
    float xv = xh[(size_t)m * 9 + c] * nm;
    x0[(size_t)m * 3 + c] = xv;
    x [(size_t)m * 3 + c] = xv;
  }
}

// ---------------- naive fused edge MLP: one block per (b,i), thread = channel n.
template<int COORD>
__global__ __launch_bounds__(256)
void edge_naive(const float* __restrict__ h,
                const float* __restrict__ We1, size_t oW1,   // [514][256] slice
                const float* __restrict__ be1, size_t ob1,
                const float* __restrict__ We2, size_t oW2,   // [256][256] slice
                const float* __restrict__ be2, size_t ob2,
                const float* __restrict__ wc3, size_t oc3,
                const float* __restrict__ x, const float* __restrict__ x0,
                const float* __restrict__ emask, const float* __restrict__ nmask,
                float* __restrict__ agg, float* __restrict__ xnext) {
  __shared__ float e1L[NN][HDIM + 1];     // 44 x 257 f32 = 45.2 KB
  __shared__ float xw[NN][3], x0w[NN][3], emw[NN], phiL[NN];
  int ni = blockIdx.x, b = ni / NN, i = ni % NN, n = threadIdx.x;
  if (n < NN) {
    for (int c = 0; c < 3; c++) {
      xw [n][c] = x [(size_t)(b * NN + n) * 3 + c];
      x0w[n][c] = x0[(size_t)(b * NN + n) * 3 + c];
    }
    emw[n] = emask[(size_t)ni * NN + n];
  }
  __syncthreads();
  float xi0 = xw[i][0], xi1 = xw[i][1], xi2 = xw[i][2];
  float yi0 = x0w[i][0], yi1 = x0w[i][1], yi2 = x0w[i][2];

  // P_i[n] = sum_k h[i][k] * We1[k][n]  + be1[n]
  float P = be1[ob1 + n];
  for (int k = 0; k < HDIM; k++)
    P += h[(size_t)ni * HDIM + k] * We1[oW1 + (size_t)k * HDIM + n];
  // Q_j[n] = sum_k h[j][k] * We1[256+k][n]
  float qacc[NN];
  #pragma unroll
  for (int j = 0; j < NN; j++) qacc[j] = 0.f;
  const float* hb = h + (size_t)(b * NN) * HDIM;
  for (int k = 0; k < HDIM; k++) {
    float w = We1[oW1 + (size_t)(256 + k) * HDIM + n];
    #pragma unroll
    for (int j = 0; j < NN; j++) qacc[j] += hb[(size_t)j * HDIM + k] * w;
  }
  float dwn  = We1[oW1 + (size_t)512 * HDIM + n];
  float d0wn = We1[oW1 + (size_t)513 * HDIM + n];
  #pragma unroll
  for (int j = 0; j < NN; j++) {
    float dx = xi0 - xw[j][0], dy = xi1 - xw[j][1], dz = xi2 - xw[j][2];
    float dd = dx * dx + dy * dy + dz * dz;
    float ex = yi0 - x0w[j][0], ey = yi1 - x0w[j][1], ez = yi2 - x0w[j][2];
    float dd0 = ex * ex + ey * ey + ez * ez;
    e1L[j][n] = silu_f(P + qacc[j] + dd * dwn + dd0 * d0wn);
  }
  __syncthreads();
  // m[j][n] = sum_k e1L[j][k] * We2[k][n]
  float macc[NN];
  #pragma unroll
  for (int j = 0; j < NN; j++) macc[j] = 0.f;
  for (int k = 0; k < HDIM; k++) {
    float w2 = We2[oW2 + (size_t)k * HDIM + n];
    #pragma unroll
    for (int j = 0; j < NN; j++) macc[j] += e1L[j][k] * w2;
  }
  float b2n = be2[ob2 + n];
  if constexpr (!COORD) {
    float s = 0.f;
    #pragma unroll
    for (int j = 0; j < NN; j++) s += silu_f(macc[j] + b2n) * emw[j];
    agg[(size_t)ni * HDIM + n] = s * 0.01f;
  } else {
    float wcn = wc3[oc3 + n];
    __syncthreads();
    #pragma unroll
    for (int j = 0; j < NN; j++) e1L[j][n] = silu_f(macc[j] + b2n) * wcn;
    __syncthreads();
    if (n < NN) {
      float ph = 0.f;
      for (int k = 0; k < HDIM; k++) ph += e1L[n][k];
      phiL[n] = ph * emw[n];
    }
    __syncthreads();
    if (n == 0) {
      float tx = 0.f, ty = 0.f, tz = 0.f;
      for (int j = 0; j < NN; j++) {
        float dx = xi0 - xw[j][0], dy = xi1 - xw[j][1], dz = xi2 - xw[j][2];
        float dd = dx * dx + dy * dy + dz * dz;
        float rinv = 1.0f / sqrtf(dd + 1e-8f);
        tx += phiL[j] * dx * rinv;
        ty += phiL[j] * dy * rinv;
        tz += phiL[j] * dz * rinv;
      }
      float nm = nmask[ni];
      xnext[(size_t)ni * 3 + 0] = (xi0 + tx * 0.01f) * nm;
      xnext[(size_t)ni * 3 + 1] = (xi1 + ty * 0.01f) * nm;
      xnext[(size_t)ni * 3 + 2] = (xi2 + tz * 0.01f) * nm;
    }
  }
}

// ---------------- naive node MLP: h = (h + silu([h,agg]@Wn1+bn1)@Wn2 + bn2) * nm
__global__ __launch_bounds__(256)
void node_mlp_naive(float* __restrict__ h, const float* __restrict__ agg,
                    const float* __restrict__ Wn1, size_t o1,
                    const float* __restrict__ bn1, size_t ob1,
                    const float* __restrict__ Wn2, size_t o2,
                    const float* __restrict__ bn2, size_t ob2,
                    const float* __restrict__ nmask) {
  __shared__ float t1L[HDIM];
  int m = blockIdx.x, n = threadIdx.x;
  float acc = bn1[ob1 + n];
  for (int k = 0; k < HDIM; k++)
    acc += h[(size_t)m * HDIM + k] * Wn1[o1 + (size_t)k * HDIM + n];
  for (int k = 0; k < HDIM; k++)
    acc += agg[(size_t)m * HDIM + k] * Wn1[o1 + (size_t)(256 + k) * HDIM + n];
  t1L[n] = silu_f(acc);
  __syncthreads();
  float acc2 = bn2[ob2 + n];
  for (int k = 0; k < HDIM; k++)
    acc2 += t1L[k] * Wn2[o2 + (size_t)k * HDIM + n];
  float nm = nmask[m];
  h[(size_t)m * HDIM + n] = (h[(size_t)m * HDIM + n] + acc2) * nm;
}

// ---------------- output: vel (mean-subtracted) + h_final  -> FLOAT32 out
__global__ __launch_bounds__(256)
void out_kernel(const float* __restrict__ h, const float* __restrict__ x,
                const float* __restrict__ x0, const float* __restrict__ nmask,
                const float* __restrict__ W_out, const float* __restrict__ b_out,
                float* __restrict__ out) {
  __shared__ float vel[NN][3];
  __shared__ float sums[4];
  int b = blockIdx.x, tid = threadIdx.x;
  if (tid < NN * 3) {
    int n = tid / 3, c = tid % 3;
    int m = b * NN + n;
    vel[n][c] = (x[(size_t)m * 3 + c] - x0[(size_t)m * 3 + c]) * nmask[m];
  }
  __syncthreads();
  if (tid < 4) {
    float s = 0.f;
    if (tid < 3) { for (int n = 0; n < NN; n++) s += vel[n][tid]; }
    else         { for (int n = 0; n < NN; n++) s += nmask[b * NN + n]; }
    sums[tid] = s;
  }
  __syncthreads();
  if (tid < NN * 3) {
    int n = tid / 3, c = tid % 3;
    int m = b * NN + n;
    float v = (vel[n][c] - sums[c] / sums[3]) * nmask[m];
    out[(size_t)m * 9 + c] = v;
  }
  for (int idx = tid; idx < NN * 6; idx += 256) {
    int n = idx / 6, c = idx % 6;
    int m = b * NN + n;
    float accv = b_out[c];
    const float* hr = h + (size_t)m * 256;
    for (int k = 0; k < 256; k++) accv += hr[k] * W_out[(size_t)k * 7 + c];
    out[(size_t)m * 9 + 3 + c] = accv * nmask[m];
  }
}

extern "C" void kernel_launch(void* const* d_in, const int* in_sizes, int n_in,
                              void* d_out, int out_size, void* d_ws, size_t ws_size,
                              hipStream_t stream) {
  const float* t       = (const float*)d_in[0];
  const float* xh      = (const float*)d_in[1];
  const float* nmask   = (const float*)d_in[2];
  const float* emask   = (const float*)d_in[3];
  const float* rep     = (const float*)d_in[4];
  const float* W_embed = (const float*)d_in[5];
  const float* b_embed = (const float*)d_in[6];
  const float* W_rep   = (const float*)d_in[7];
  const float* b_rep   = (const float*)d_in[8];
  const float* We1     = (const float*)d_in[9];
  const float* be1     = (const float*)d_in[10];
  const float* We2     = (const float*)d_in[11];
  const float* be2     = (const float*)d_in[12];
  const float* Wn1     = (const float*)d_in[13];
  const float* bn1     = (const float*)d_in[14];
  const float* Wn2     = (const float*)d_in[15];
  const float* bn2     = (const float*)d_in[16];
  const float* Wc1     = (const float*)d_in[17];
  const float* bc1     = (const float*)d_in[18];
  const float* Wc2     = (const float*)d_in[19];
  const float* bc2     = (const float*)d_in[20];
  const float* Wc3     = (const float*)d_in[21];
  const float* W_out   = (const float*)d_in[22];
  const float* b_out   = (const float*)d_in[23];

  char* p = (char*)d_ws;
  auto alloc = [&](size_t bytes) { char* r = p; p += (bytes + 255) & ~(size_t)255; return r; };
  float* h     = (float*)alloc((size_t)NODES * 256 * 4);
  float* agg   = (float*)alloc((size_t)NODES * 256 * 4);
  float* x0buf = (float*)alloc((size_t)NODES * 3 * 4);
  float* xA    = (float*)alloc((size_t)NODES * 3 * 4);
  float* xB    = (float*)alloc((size_t)NODES * 3 * 4);
  float* rproj = (float*)alloc((size_t)BSZ * 256 * 4);

  repproj_kernel<<<BSZ, 256, 0, stream>>>(rep, W_rep, b_rep, rproj);
  embed_kernel<<<NODES, 256, 0, stream>>>(xh, t, nmask, W_embed, b_embed, rproj,
                                          h, x0buf, xA);

  float* xcur = xA;
  for (int l = 0; l < 4; l++) {
    float* xnext = (l & 1) ? xA : xB;
    for (int s = 0; s < 2; s++) {
      int k = 2 * l + s;
      size_t oWe1 = (size_t)k * 514 * 256, obe1 = (size_t)k * 256;
      size_t oWe2 = (size_t)k * 256 * 256, obe2 = (size_t)k * 256;
      size_t oWn1 = (size_t)k * 512 * 256, obn1 = (size_t)k * 256;
      size_t oWn2 = (size_t)k * 256 * 256, obn2 = (size_t)k * 256;
      edge_naive<0><<<NODES, 256, 0, stream>>>(
          h, We1, oWe1, be1, obe1, We2, oWe2, be2, obe2, Wc3, 0,
          xcur, x0buf, emask, nmask, agg, nullptr);
      node_mlp_naive<<<NODES, 256, 0, stream>>>(
          h, agg, Wn1, oWn1, bn1, obn1, Wn2, oWn2, bn2, obn2, nmask);
    }
    size_t oWc1 = (size_t)l * 514 * 256, obc1 = (size_t)l * 256;
    size_t oWc2 = (size_t)l * 256 * 256, obc2 = (size_t)l * 256;
    size_t oc3  = (size_t)l * 256;
    edge_naive<1><<<NODES, 256, 0, stream>>>(
        h, Wc1, oWc1, bc1, obc1, Wc2, oWc2, bc2, obc2, Wc3, oc3,
        xcur, x0buf, emask, nmask, nullptr, xnext);
    xcur = xnext;
  }

  out_kernel<<<BSZ, 256, 0, stream>>>(h, xcur, x0buf, nmask, W_out, b_out,
                                      (float*)d_out);
}

// Round 10
// 2069.677 us; speedup vs baseline: 5.7556x; 5.7556x over previous
//
#include <hip/hip_runtime.h>

typedef __bf16 bf16_t;
typedef __bf16 bf16x8 __attribute__((ext_vector_type(8)));
typedef float  f32x4  __attribute__((ext_vector_type(4)));

#define BSZ 64
#define NNODE 44
#define NODES (BSZ*NNODE)      /* 2816 */

__device__ __forceinline__ float  bf2f(bf16_t v){ return (float)v; }
__device__ __forceinline__ bf16_t f2bf(float v){ return (bf16_t)v; }
__device__ __forceinline__ float  silu_f(float v){ return v / (1.0f + __expf(-v)); }

// ---------------- rproj[b][c] = rep[b]@W_rep[:,c] + b_rep[c]
__global__ __launch_bounds__(256)
void repproj_kernel(const float* __restrict__ rep, const float* __restrict__ W_rep,
                    const float* __restrict__ b_rep, float* __restrict__ out) {
  int b = blockIdx.x, c = threadIdx.x;
  float acc = b_rep[c];
  const float* r = rep + (size_t)b * 512;
  for (int k = 0; k < 512; k++) acc += r[k] * W_rep[(size_t)k * 256 + c];
  out[(size_t)b * 256 + c] = acc;
}

// ---------------- embedding; writes h_f32, cat1[:, :256], x0, xA
__global__ __launch_bounds__(256)
void embed_kernel(const float* __restrict__ xh, const float* __restrict__ t,
                  const float* __restrict__ nmask,
                  const float* __restrict__ W_embed, const float* __restrict__ b_embed,
                  const float* __restrict__ repproj,
                  float* __restrict__ h_f32, bf16_t* __restrict__ cat1,
                  float* __restrict__ x0, float* __restrict__ x) {
  int m = blockIdx.x;
  int b = m / NNODE;
  int c = threadIdx.x;
  float nm = nmask[m];
  float acc = b_embed[c] + repproj[(size_t)b * 256 + c];
  for (int kk = 0; kk < 6; kk++)
    acc += xh[(size_t)m * 9 + 3 + kk] * nm * W_embed[(size_t)kk * 256 + c];
  acc += t[b] * W_embed[6 * 256 + c];
  h_f32[(size_t)m * 256 + c] = acc;
  cat1 [(size_t)m * 512 + c] = f2bf(acc);
  if (c < 3) {
    float xv = xh[(size_t)m * 9 + c] * nm;
    x0[(size_t)m * 3 + c] = xv;
    x [(size_t)m * 3 + c] = xv;
  }
}

// ---------------- node GEMM, BM=64 BN=64 BK=32, 4 waves of 32x32.
// B staged in-kernel from k-major f32 W[(kof+k)][256] with f32->bf16 convert.
// MODE 0: PQ(f32) at [row*512 + z*256 + col] = A@W
// MODE 1: outB = silu(A@W + bias)            (bf16)
// MODE 2: h = (hold + A@W + bias)*nmask -> h_f32(hnew), cat1[:, :256](catb)
template<int MODE>
__global__ __launch_bounds__(256)
void gemm_node(const bf16_t* __restrict__ A, int lda,
               const float* __restrict__ W, size_t oW,
               const float* __restrict__ bias, size_t ob, int K,
               float* __restrict__ outPQ,
               bf16_t* __restrict__ outB,
               const float* __restrict__ hold,
               float* __restrict__ hnew,
               bf16_t* __restrict__ catb,
               const float* __restrict__ nmask) {
  __shared__ __align__(16) bf16_t As[64][40];
  __shared__ __align__(16) bf16_t Bs[64][40];
  int tid = threadIdx.x;
  int m0 = blockIdx.y * 64, n0 = blockIdx.x * 64;
  int kof = (MODE == 0) ? (int)blockIdx.z * 256 : 0;
  int w = tid >> 6, lane = tid & 63, q = lane >> 4, lr = lane & 15;
  int wm = w & 1, wn = w >> 1;
  f32x4 acc[2][2];
  for (int a = 0; a < 2; a++) for (int bb = 0; bb < 2; bb++)
    for (int rr = 0; rr < 4; rr++) acc[a][bb][rr] = 0.0f;
  int lrow = tid >> 2, lc = tid & 3;      // A staging: row 0..63, 8-col chunk
  int nn = tid & 63, kr4 = tid >> 6;      // B staging: col n, k-phase
  for (int k0 = 0; k0 < K; k0 += 32) {
    f32x4 av = *(const f32x4*)(A + (size_t)(m0 + lrow) * lda + k0 + lc * 8);
    bf16_t bw[8];
    for (int p = 0; p < 8; p++)
      bw[p] = f2bf(W[oW + (size_t)(kof + k0 + kr4 + p * 4) * 256 + n0 + nn]);
    __syncthreads();
    *(f32x4*)(&As[lrow][lc * 8]) = av;
    for (int p = 0; p < 8; p++) Bs[nn][kr4 + p * 4] = bw[p];
    __syncthreads();
    bf16x8 af[2], bfr[2];
    for (int mt = 0; mt < 2; mt++) af[mt]  = *(const bf16x8*)(&As[wm * 32 + mt * 16 + lr][q * 8]);
    for (int nt = 0; nt < 2; nt++) bfr[nt] = *(const bf16x8*)(&Bs[wn * 32 + nt * 16 + lr][q * 8]);
    for (int mt = 0; mt < 2; mt++)
      for (int nt = 0; nt < 2; nt++)
        acc[mt][nt] = __builtin_amdgcn_mfma_f32_16x16x32_bf16(af[mt], bfr[nt], acc[mt][nt], 0, 0, 0);
  }
  for (int mt = 0; mt < 2; mt++)
    for (int nt = 0; nt < 2; nt++) {
      int col = n0 + wn * 32 + nt * 16 + lr;
      for (int rr = 0; rr < 4; rr++) {
        int row = m0 + wm * 32 + mt * 16 + q * 4 + rr;
        float v = acc[mt][nt][rr];
        if constexpr (MODE == 0) {
          outPQ[(size_t)row * 512 + (size_t)blockIdx.z * 256 + col] = v;
        } else if constexpr (MODE == 1) {
          v = silu_f(v + bias[ob + col]);
          outB[(size_t)row * 256 + col] = f2bf(v);
        } else {
          v = v + bias[ob + col] + hold[(size_t)row * 256 + col];
          v *= nmask[row];
          hnew[(size_t)row * 256 + col] = v;
          catb[(size_t)row * 512 + col] = f2bf(v);
        }
      }
    }
}

// ---------------- fused edge kernel: one workgroup per (b,i).
// d (from xcur) and d0 (from x0g) computed in-kernel from LDS-staged x.
// E1 = silu(P_i + Q_j + d*w512 + d0*w513 + be1) in LDS (48x256 over j),
// E2pre = E1 @ We2 + b2 via MFMA.
// COORD=0: agg -> cat1[:, 256:]; COORD=1: phi -> xnext = (xcur + sum/100)*nmask.
template<int COORD>
__global__ __launch_bounds__(256)
void edge_kernel(const float* __restrict__ PQ,
                 const float* __restrict__ We1raw, size_t oW1,  // [514][256] slice
                 const float* __restrict__ be1,   size_t ob1,
                 const float* __restrict__ W2,    size_t oW2,   // [256][256] slice
                 const float* __restrict__ b2,    size_t ob2,
                 const float* __restrict__ wc3,   size_t oc3,
                 const float* __restrict__ xcur,
                 const float* __restrict__ x0g,
                 const float* __restrict__ emask,
                 const float* __restrict__ nmask,
                 bf16_t* __restrict__ aggout,
                 float* __restrict__ xnext) {
  __shared__ __align__(16) bf16_t Ae[48][264];
  __shared__ __align__(16) bf16_t Bs[256][72];
  __shared__ float  xjL[48][3], x0jL[48][3];
  __shared__ float  emLDS[48];
  __shared__ float  phiLDS[4][48];
  int ni = blockIdx.x;
  int b = ni / NNODE;
  int i = ni % NNODE;
  size_t e0 = (size_t)ni * NNODE;
  int tid = threadIdx.x;
  if (tid < NNODE) {
    for (int c = 0; c < 3; c++) {
      xjL [tid][c] = xcur[(size_t)(b * NNODE + tid) * 3 + c];
      x0jL[tid][c] = x0g [(size_t)(b * NNODE + tid) * 3 + c];
    }
  }
  if (tid < 48) emLDS[tid] = (tid < NNODE) ? emask[e0 + tid] : 0.f;
  __syncthreads();
  float xi0 = xjL[i][0], xi1 = xjL[i][1], xi2 = xjL[i][2];
  float y0 = x0jL[i][0], y1 = x0jL[i][1], y2 = x0jL[i][2];
  // ---- A formation (thread == output channel n)
  {
    int n = tid;
    float pi   = PQ[(size_t)ni * 512 + n];
    float w512 = We1raw[oW1 + 512 * 256 + n];
    float w513 = We1raw[oW1 + 513 * 256 + n];
    float b1   = be1[ob1 + n];
    for (int j = 0; j < 48; j++) {
      float v = 0.f;
      if (j < NNODE) {
        float dx = xi0 - xjL[j][0], dy = xi1 - xjL[j][1], dz = xi2 - xjL[j][2];
        float dd = dx * dx + dy * dy + dz * dz;
        float ex = y0 - x0jL[j][0], ey = y1 - x0jL[j][1], ez = y2 - x0jL[j][2];
        float dd0 = ex * ex + ey * ey + ez * ez;
        float qj  = PQ[(size_t)(b * NNODE + j) * 512 + 256 + n];
        v = silu_f(pi + qj + dd * w512 + dd0 * w513 + b1);
      }
      Ae[j][n] = f2bf(v);
    }
  }
  int w = tid >> 6, lane = tid & 63, q = lane >> 4, lr = lane & 15;
  f32x4 acc[3][4];
  for (int mt = 0; mt < 3; mt++) for (int nt = 0; nt < 4; nt++)
    for (int rr = 0; rr < 4; rr++) acc[mt][nt][rr] = 0.0f;
  // ---- K loop
  for (int k0 = 0; k0 < 256; k0 += 64) {
    __syncthreads();
    for (int kr = 0; kr < 64; kr++)
      Bs[tid][kr] = f2bf(W2[oW2 + (size_t)(k0 + kr) * 256 + tid]);
    __syncthreads();
    for (int kk = 0; kk < 64; kk += 32) {
      bf16x8 af[3], bfr[4];
      for (int mt = 0; mt < 3; mt++) af[mt]  = *(const bf16x8*)(&Ae[mt * 16 + lr][k0 + kk + q * 8]);
      for (int nt = 0; nt < 4; nt++) bfr[nt] = *(const bf16x8*)(&Bs[w * 64 + nt * 16 + lr][kk + q * 8]);
      for (int mt = 0; mt < 3; mt++)
        for (int nt = 0; nt < 4; nt++)
          acc[mt][nt] = __builtin_amdgcn_mfma_f32_16x16x32_bf16(af[mt], bfr[nt], acc[mt][nt], 0, 0, 0);
    }
  }
  // ---- epilogue
  if constexpr (!COORD) {
    for (int nt = 0; nt < 4; nt++) {
      int col = w * 64 + nt * 16 + lr;
      float bcol = b2[ob2 + col];
      float s = 0.f;
      for (int mt = 0; mt < 3; mt++)
        for (int rr = 0; rr < 4; rr++) {
          int row = mt * 16 + q * 4 + rr;
          s += silu_f(acc[mt][nt][rr] + bcol) * emLDS[row];
        }
      s += __shfl_xor(s, 16, 64);
      s += __shfl_xor(s, 32, 64);
      if (q == 0) aggout[(size_t)ni * 512 + 256 + col] = f2bf(s * 0.01f);
    }
  } else {
    for (int mt = 0; mt < 3; mt++) {
      float rs[4] = {0.f, 0.f, 0.f, 0.f};
      for (int nt = 0; nt < 4; nt++) {
        int col = w * 64 + nt * 16 + lr;
        float bcol = b2[ob2 + col];
        float wc   = wc3[oc3 + col];
        for (int rr = 0; rr < 4; rr++)
          rs[rr] += silu_f(acc[mt][nt][rr] + bcol) * wc;
      }
      for (int off = 1; off <= 8; off <<= 1)
        for (int rr = 0; rr < 4; rr++) rs[rr] += __shfl_xor(rs[rr], off, 64);
      if (lr == 0)
        for (int rr = 0; rr < 4; rr++)
          phiLDS[w][mt * 16 + q * 4 + rr] = rs[rr];
    }
    __syncthreads();
    if (tid < 64) {
      int j = lane;
      float tx = 0.f, ty = 0.f, tz = 0.f;
      if (j < NNODE) {
        float ph = 0.f;
        for (int ww = 0; ww < 4; ww++) ph += phiLDS[ww][j];
        ph *= emLDS[j];
        float dx = xi0 - xjL[j][0], dy = xi1 - xjL[j][1], dz = xi2 - xjL[j][2];
        float dd = dx * dx + dy * dy + dz * dz;
        float rinv = 1.0f / sqrtf(dd + 1e-8f);
        tx = ph * dx * rinv;
        ty = ph * dy * rinv;
        tz = ph * dz * rinv;
      }
      for (int off = 1; off <= 32; off <<= 1) {
        tx += __shfl_xor(tx, off, 64);
        ty += __shfl_xor(ty, off, 64);
        tz += __shfl_xor(tz, off, 64);
      }
      if (lane == 0) {
        float nm = nmask[ni];
        xnext[(size_t)ni * 3 + 0] = (xjL[i][0] + tx * 0.01f) * nm;
        xnext[(size_t)ni * 3 + 1] = (xjL[i][1] + ty * 0.01f) * nm;
        xnext[(size_t)ni * 3 + 2] = (xjL[i][2] + tz * 0.01f) * nm;
      }
    }
  }
}

// ---------------- output: vel (mean-subtracted) + h_final -> FLOAT32 out
__global__ __launch_bounds__(256)
void out_kernel(const float* __restrict__ h, const float* __restrict__ x,
                const float* __restrict__ x0, const float* __restrict__ nmask,
                const float* __restrict__ W_out, const float* __restrict__ b_out,
                float* __restrict__ out) {
  __shared__ float vel[NNODE][3];
  __shared__ float sums[4];
  int b = blockIdx.x, tid = threadIdx.x;
  if (tid < NNODE * 3) {
    int n = tid / 3, c = tid % 3;
    int m = b * NNODE + n;
    vel[n][c] = (x[(size_t)m * 3 + c] - x0[(size_t)m * 3 + c]) * nmask[m];
  }
  __syncthreads();
  if (tid < 4) {
    float s = 0.f;
    if (tid < 3) { for (int n = 0; n < NNODE; n++) s += vel[n][tid]; }
    else         { for (int n = 0; n < NNODE; n++) s += nmask[b * NNODE + n]; }
    sums[tid] = s;
  }
  __syncthreads();
  if (tid < NNODE * 3) {
    int n = tid / 3, c = tid % 3;
    int m = b * NNODE + n;
    float v = (vel[n][c] - sums[c] / sums[3]) * nmask[m];
    out[(size_t)m * 9 + c] = v;
  }
  for (int idx = tid; idx < NNODE * 6; idx += 256) {
    int n = idx / 6, c = idx % 6;
    int m = b * NNODE + n;
    float accv = b_out[c];
    const float* hr = h + (size_t)m * 256;
    for (int k = 0; k < 256; k++) accv += hr[k] * W_out[(size_t)k * 7 + c];
    out[(size_t)m * 9 + 3 + c] = accv * nmask[m];
  }
}

extern "C" void kernel_launch(void* const* d_in, const int* in_sizes, int n_in,
                              void* d_out, int out_size, void* d_ws, size_t ws_size,
                              hipStream_t stream) {
  const float* t       = (const float*)d_in[0];
  const float* xh      = (const float*)d_in[1];
  const float* nmask   = (const float*)d_in[2];
  const float* emask   = (const float*)d_in[3];
  const float* rep     = (const float*)d_in[4];
  const float* W_embed = (const float*)d_in[5];
  const float* b_embed = (const float*)d_in[6];
  const float* W_rep   = (const float*)d_in[7];
  const float* b_rep   = (const float*)d_in[8];
  const float* We1     = (const float*)d_in[9];
  const float* be1     = (const float*)d_in[10];
  const float* We2     = (const float*)d_in[11];
  const float* be2     = (const float*)d_in[12];
  const float* Wn1     = (const float*)d_in[13];
  const float* bn1     = (const float*)d_in[14];
  const float* Wn2     = (const float*)d_in[15];
  const float* bn2     = (const float*)d_in[16];
  const float* Wc1     = (const float*)d_in[17];
  const float* bc1     = (const float*)d_in[18];
  const float* Wc2     = (const float*)d_in[19];
  const float* bc2     = (const float*)d_in[20];
  const float* Wc3     = (const float*)d_in[21];
  const float* W_out   = (const float*)d_in[22];
  const float* b_out   = (const float*)d_in[23];

  char* p = (char*)d_ws;
  auto alloc = [&](size_t bytes) { char* r = p; p += (bytes + 255) & ~(size_t)255; return r; };
  float*  h_f32 = (float*) alloc((size_t)NODES * 256 * 4);   // 2.88 MB
  bf16_t* cat1  = (bf16_t*)alloc((size_t)NODES * 512 * 2);   // 2.88 MB
  bf16_t* t1    = (bf16_t*)alloc((size_t)NODES * 256 * 2);   // 1.44 MB
  float*  PQ    = (float*) alloc((size_t)NODES * 512 * 4);   // 5.77 MB
  float*  x0buf = (float*) alloc((size_t)NODES * 3 * 4);
  float*  xA    = (float*) alloc((size_t)NODES * 3 * 4);
  float*  xB    = (float*) alloc((size_t)NODES * 3 * 4);
  float*  rproj = (float*) alloc((size_t)BSZ * 256 * 4);
  // total ~13.1 MB

  repproj_kernel<<<BSZ, 256, 0, stream>>>(rep, W_rep, b_rep, rproj);
  embed_kernel<<<NODES, 256, 0, stream>>>(xh, t, nmask, W_embed, b_embed, rproj,
                                          h_f32, cat1, x0buf, xA);

  float* xcur = xA;
  for (int l = 0; l < 4; l++) {
    float* xnext = (l & 1) ? xA : xB;
    for (int s = 0; s < 2; s++) {
      int k = 2 * l + s;
      size_t oWe1 = (size_t)k * 514 * 256, obe1 = (size_t)k * 256;
      size_t oWe2 = (size_t)k * 256 * 256, obe2 = (size_t)k * 256;
      size_t oWn1 = (size_t)k * 512 * 256, obn1 = (size_t)k * 256;
      size_t oWn2 = (size_t)k * 256 * 256, obn2 = (size_t)k * 256;
      gemm_node<0><<<dim3(4, 44, 2), 256, 0, stream>>>(
          cat1, 512, We1, oWe1, nullptr, 0, 256,
          PQ, nullptr, nullptr, nullptr, nullptr, nullptr);
      edge_kernel<0><<<NODES, 256, 0, stream>>>(
          PQ, We1, oWe1, be1, obe1, We2, oWe2, be2, obe2, Wc3, 0,
          xcur, x0buf, emask, nmask, cat1, nullptr);
      gemm_node<1><<<dim3(4, 44, 1), 256, 0, stream>>>(
          cat1, 512, Wn1, oWn1, bn1, obn1, 512,
          nullptr, t1, nullptr, nullptr, nullptr, nullptr);
      gemm_node<2><<<dim3(4, 44, 1), 256, 0, stream>>>(
          t1, 256, Wn2, oWn2, bn2, obn2, 256,
          nullptr, nullptr, h_f32, h_f32, cat1, nmask);
    }
    size_t oWc1 = (size_t)l * 514 * 256, obc1 = (size_t)l * 256;
    size_t oWc2 = (size_t)l * 256 * 256, obc2 = (size_t)l * 256;
    size_t oc3  = (size_t)l * 256;
    gemm_node<0><<<dim3(4, 44, 2), 256, 0, stream>>>(
        cat1, 512, Wc1, oWc1, nullptr, 0, 256,
        PQ, nullptr, nullptr, nullptr, nullptr, nullptr);
    edge_kernel<1><<<NODES, 256, 0, stream>>>(
        PQ, Wc1, oWc1, bc1, obc1, Wc2, oWc2, bc2, obc2, Wc3, oc3,
        xcur, x0buf, emask, nmask, nullptr, xnext);
    xcur = xnext;
  }

  out_kernel<<<BSZ, 256, 0, stream>>>(h_f32, xcur, x0buf, nmask, W_out, b_out,
                                      (float*)d_out);
}

// Round 11
// 1581.960 us; speedup vs baseline: 7.5300x; 1.3083x over previous
//
#include <hip/hip_runtime.h>

typedef __bf16 bf16_t;
typedef __bf16 bf16x8 __attribute__((ext_vector_type(8)));
typedef float  f32x4  __attribute__((ext_vector_type(4)));

#define BSZ 64
#define NNODE 44
#define NODES (BSZ*NNODE)      /* 2816 */

__device__ __forceinline__ float  bf2f(bf16_t v){ return (float)v; }
__device__ __forceinline__ bf16_t f2bf(float v){ return (bf16_t)v; }
__device__ __forceinline__ float  silu_f(float v){ return v / (1.0f + __expf(-v)); }

// ---------------- batched transpose + f32->bf16: src (G,R,256) -> dst (G,256,ldo)
// dst[g][n][r] = src[g][r][n]
__global__ void transpose_wb(const float* __restrict__ src, bf16_t* __restrict__ dst,
                             int R, int ldo) {
  __shared__ bf16_t tile[32][33];
  int g = blockIdx.z;
  src += (size_t)g * R * 256;
  dst += (size_t)g * 256 * ldo;
  int n0 = blockIdx.x * 32, r0 = blockIdx.y * 32;
  int tx = threadIdx.x, ty = threadIdx.y;   // 32 x 8
  for (int p = 0; p < 32; p += 8) {
    int r = r0 + ty + p;
    if (r < R) tile[ty + p][tx] = f2bf(src[(size_t)r * 256 + n0 + tx]);
  }
  __syncthreads();
  for (int p = 0; p < 32; p += 8) {
    int r = r0 + tx;
    if (r < R) dst[(size_t)(n0 + ty + p) * ldo + r] = tile[tx][ty + p];
  }
}

// ---------------- rproj[b][c] = rep[b]@W_rep[:,c] + b_rep[c]
__global__ __launch_bounds__(256)
void repproj_kernel(const float* __restrict__ rep, const float* __restrict__ W_rep,
                    const float* __restrict__ b_rep, float* __restrict__ out) {
  int b = blockIdx.x, c = threadIdx.x;
  float acc = b_rep[c];
  const float* r = rep + (size_t)b * 512;
  for (int k = 0; k < 512; k++) acc += r[k] * W_rep[(size_t)k * 256 + c];
  out[(size_t)b * 256 + c] = acc;
}

// ---------------- embedding; writes h_f32, cat1[:, :256], x0, xA
__global__ __launch_bounds__(256)
void embed_kernel(const float* __restrict__ xh, const float* __restrict__ t,
                  const float* __restrict__ nmask,
                  const float* __restrict__ W_embed, const float* __restrict__ b_embed,
                  const float* __restrict__ repproj,
                  float* __restrict__ h_f32, bf16_t* __restrict__ cat1,
                  float* __restrict__ x0, float* __restrict__ x) {
  int m = blockIdx.x;
  int b = m / NNODE;
  int c = threadIdx.x;
  float nm = nmask[m];
  float acc = b_embed[c] + repproj[(size_t)b * 256 + c];
  for (int kk = 0; kk < 6; kk++)
    acc += xh[(size_t)m * 9 + 3 + kk] * nm * W_embed[(size_t)kk * 256 + c];
  acc += t[b] * W_embed[6 * 256 + c];
  h_f32[(size_t)m * 256 + c] = acc;
  cat1 [(size_t)m * 512 + c] = f2bf(acc);
  if (c < 3) {
    float xv = xh[(size_t)m * 9 + c] * nm;
    x0[(size_t)m * 3 + c] = xv;
    x [(size_t)m * 3 + c] = xv;
  }
}

// ---------------- node GEMM, BM=64 BN=64, 4 waves of 32x32. ZERO LDS:
// A (bf16 row-major) and BT (bf16 n-major [n][ldbt]) fragments direct from global.
// MODE 0: PQ(f32) at [row*512 + z*256 + col] = A@W
// MODE 1: outB = silu(A@W + bias)            (bf16)
// MODE 2: h = (hold + A@W + bias)*nmask -> h_f32(hnew), cat1[:, :256](catb)
template<int MODE>
__global__ __launch_bounds__(256)
void gemm_node(const bf16_t* __restrict__ A, int lda,
               const bf16_t* __restrict__ BT, int ldbt,
               const float* __restrict__ bias, size_t ob, int K,
               float* __restrict__ outPQ,
               bf16_t* __restrict__ outB,
               const float* __restrict__ hold,
               float* __restrict__ hnew,
               bf16_t* __restrict__ catb,
               const float* __restrict__ nmask) {
  int tid = threadIdx.x;
  int m0 = blockIdx.y * 64, n0 = blockIdx.x * 64;
  int kof = (MODE == 0) ? (int)blockIdx.z * 256 : 0;
  int w = tid >> 6, lane = tid & 63, q = lane >> 4, lr = lane & 15;
  int wm = w & 1, wn = w >> 1;
  f32x4 acc[2][2];
  for (int a = 0; a < 2; a++) for (int bb = 0; bb < 2; bb++)
    for (int rr = 0; rr < 4; rr++) acc[a][bb][rr] = 0.0f;
  const bf16_t* Arow0 = A  + (size_t)(m0 + wm * 32 + lr) * lda;
  const bf16_t* Brow0 = BT + (size_t)(n0 + wn * 32 + lr) * ldbt + kof;
  for (int k0 = 0; k0 < K; k0 += 32) {
    bf16x8 af[2], bfr[2];
    for (int mt = 0; mt < 2; mt++)
      af[mt]  = *(const bf16x8*)(Arow0 + (size_t)mt * 16 * lda + k0 + q * 8);
    for (int nt = 0; nt < 2; nt++)
      bfr[nt] = *(const bf16x8*)(Brow0 + (size_t)nt * 16 * ldbt + k0 + q * 8);
    for (int mt = 0; mt < 2; mt++)
      for (int nt = 0; nt < 2; nt++)
        acc[mt][nt] = __builtin_amdgcn_mfma_f32_16x16x32_bf16(af[mt], bfr[nt], acc[mt][nt], 0, 0, 0);
  }
  for (int mt = 0; mt < 2; mt++)
    for (int nt = 0; nt < 2; nt++) {
      int col = n0 + wn * 32 + nt * 16 + lr;
      for (int rr = 0; rr < 4; rr++) {
        int row = m0 + wm * 32 + mt * 16 + q * 4 + rr;
        float v = acc[mt][nt][rr];
        if constexpr (MODE == 0) {
          outPQ[(size_t)row * 512 + (size_t)blockIdx.z * 256 + col] = v;
        } else if constexpr (MODE == 1) {
          v = silu_f(v + bias[ob + col]);
          outB[(size_t)row * 256 + col] = f2bf(v);
        } else {
          v = v + bias[ob + col] + hold[(size_t)row * 256 + col];
          v *= nmask[row];
          hnew[(size_t)row * 256 + col] = v;
          catb[(size_t)row * 512 + col] = f2bf(v);
        }
      }
    }
}

// ---------------- fused edge kernel: one workgroup per (b,i).
// E1 = silu(P_i + Q_j + d*w512 + d0*w513 + be1) in LDS (48x256 over j),
// E2pre = E1 @ We2 + b2 via MFMA; B fragments DIRECT from bf16 W2T (L2-resident).
// COORD=0: agg -> cat1[:, 256:]; COORD=1: phi -> xnext = (xcur + sum/100)*nmask.
template<int COORD>
__global__ __launch_bounds__(256)
void edge_kernel(const float* __restrict__ PQ,
                 const float* __restrict__ We1raw, size_t oW1,  // f32 [514][256] slice
                 const float* __restrict__ be1,   size_t ob1,
                 const bf16_t* __restrict__ W2T,  size_t oW2,   // bf16 [256 n][256 k] slice
                 const float* __restrict__ b2,    size_t ob2,
                 const float* __restrict__ wc3,   size_t oc3,
                 const float* __restrict__ xcur,
                 const float* __restrict__ x0g,
                 const float* __restrict__ emask,
                 const float* __restrict__ nmask,
                 bf16_t* __restrict__ aggout,
                 float* __restrict__ xnext) {
  __shared__ __align__(16) bf16_t Ae[48][264];
  __shared__ float  xjL[48][3], x0jL[48][3];
  __shared__ float  emLDS[48];
  __shared__ float  phiLDS[4][48];
  int ni = blockIdx.x;
  int b = ni / NNODE;
  int i = ni % NNODE;
  size_t e0 = (size_t)ni * NNODE;
  int tid = threadIdx.x;
  if (tid < NNODE) {
    for (int c = 0; c < 3; c++) {
      xjL [tid][c] = xcur[(size_t)(b * NNODE + tid) * 3 + c];
      x0jL[tid][c] = x0g [(size_t)(b * NNODE + tid) * 3 + c];
    }
  }
  if (tid < 48) emLDS[tid] = (tid < NNODE) ? emask[e0 + tid] : 0.f;
  __syncthreads();
  float xi0 = xjL[i][0], xi1 = xjL[i][1], xi2 = xjL[i][2];
  float y0 = x0jL[i][0], y1 = x0jL[i][1], y2 = x0jL[i][2];
  // ---- A formation (thread == output channel n)
  {
    int n = tid;
    float pi   = PQ[(size_t)ni * 512 + n];
    float w512 = We1raw[oW1 + 512 * 256 + n];
    float w513 = We1raw[oW1 + 513 * 256 + n];
    float b1   = be1[ob1 + n];
    for (int j = 0; j < 48; j++) {
      float v = 0.f;
      if (j < NNODE) {
        float dx = xi0 - xjL[j][0], dy = xi1 - xjL[j][1], dz = xi2 - xjL[j][2];
        float dd = dx * dx + dy * dy + dz * dz;
        float ex = y0 - x0jL[j][0], ey = y1 - x0jL[j][1], ez = y2 - x0jL[j][2];
        float dd0 = ex * ex + ey * ey + ez * ez;
        float qj  = PQ[(size_t)(b * NNODE + j) * 512 + 256 + n];
        v = silu_f(pi + qj + dd * w512 + dd0 * w513 + b1);
      }
      Ae[j][n] = f2bf(v);
    }
  }
  __syncthreads();
  int w = tid >> 6, lane = tid & 63, q = lane >> 4, lr = lane & 15;
  f32x4 acc[3][4];
  for (int mt = 0; mt < 3; mt++) for (int nt = 0; nt < 4; nt++)
    for (int rr = 0; rr < 4; rr++) acc[mt][nt][rr] = 0.0f;
  const bf16_t* Bbase = W2T + oW2 + (size_t)(w * 64 + lr) * 256;
  // ---- K loop: A frags from LDS, B frags direct from global (L2-resident)
  #pragma unroll
  for (int kk = 0; kk < 256; kk += 32) {
    bf16x8 af[3], bfr[4];
    for (int mt = 0; mt < 3; mt++)
      af[mt]  = *(const bf16x8*)(&Ae[mt * 16 + lr][kk + q * 8]);
    for (int nt = 0; nt < 4; nt++)
      bfr[nt] = *(const bf16x8*)(Bbase + (size_t)nt * 16 * 256 + kk + q * 8);
    for (int mt = 0; mt < 3; mt++)
      for (int nt = 0; nt < 4; nt++)
        acc[mt][nt] = __builtin_amdgcn_mfma_f32_16x16x32_bf16(af[mt], bfr[nt], acc[mt][nt], 0, 0, 0);
  }
  // ---- epilogue
  if constexpr (!COORD) {
    for (int nt = 0; nt < 4; nt++) {
      int col = w * 64 + nt * 16 + lr;
      float bcol = b2[ob2 + col];
      float s = 0.f;
      for (int mt = 0; mt < 3; mt++)
        for (int rr = 0; rr < 4; rr++) {
          int row = mt * 16 + q * 4 + rr;
          s += silu_f(acc[mt][nt][rr] + bcol) * emLDS[row];
        }
      s += __shfl_xor(s, 16, 64);
      s += __shfl_xor(s, 32, 64);
      if (q == 0) aggout[(size_t)ni * 512 + 256 + col] = f2bf(s * 0.01f);
    }
  } else {
    for (int mt = 0; mt < 3; mt++) {
      float rs[4] = {0.f, 0.f, 0.f, 0.f};
      for (int nt = 0; nt < 4; nt++) {
        int col = w * 64 + nt * 16 + lr;
        float bcol = b2[ob2 + col];
        float wc   = wc3[oc3 + col];
        for (int rr = 0; rr < 4; rr++)
          rs[rr] += silu_f(acc[mt][nt][rr] + bcol) * wc;
      }
      for (int off = 1; off <= 8; off <<= 1)
        for (int rr = 0; rr < 4; rr++) rs[rr] += __shfl_xor(rs[rr], off, 64);
      if (lr == 0)
        for (int rr = 0; rr < 4; rr++)
          phiLDS[w][mt * 16 + q * 4 + rr] = rs[rr];
    }
    __syncthreads();
    if (tid < 64) {
      int j = lane;
      float tx = 0.f, ty = 0.f, tz = 0.f;
      if (j < NNODE) {
        float ph = 0.f;
        for (int ww = 0; ww < 4; ww++) ph += phiLDS[ww][j];
        ph *= emLDS[j];
        float dx = xi0 - xjL[j][0], dy = xi1 - xjL[j][1], dz = xi2 - xjL[j][2];
        float dd = dx * dx + dy * dy + dz * dz;
        float rinv = 1.0f / sqrtf(dd + 1e-8f);
        tx = ph * dx * rinv;
        ty = ph * dy * rinv;
        tz = ph * dz * rinv;
      }
      for (int off = 1; off <= 32; off <<= 1) {
        tx += __shfl_xor(tx, off, 64);
        ty += __shfl_xor(ty, off, 64);
        tz += __shfl_xor(tz, off, 64);
      }
      if (lane == 0) {
        float nm = nmask[ni];
        xnext[(size_t)ni * 3 + 0] = (xjL[i][0] + tx * 0.01f) * nm;
        xnext[(size_t)ni * 3 + 1] = (xjL[i][1] + ty * 0.01f) * nm;
        xnext[(size_t)ni * 3 + 2] = (xjL[i][2] + tz * 0.01f) * nm;
      }
    }
  }
}

// ---------------- output: vel (mean-subtracted) + h_final -> FLOAT32 out
__global__ __launch_bounds__(256)
void out_kernel(const float* __restrict__ h, const float* __restrict__ x,
                const float* __restrict__ x0, const float* __restrict__ nmask,
                const float* __restrict__ W_out, const float* __restrict__ b_out,
                float* __restrict__ out) {
  __shared__ float vel[NNODE][3];
  __shared__ float sums[4];
  int b = blockIdx.x, tid = threadIdx.x;
  if (tid < NNODE * 3) {
    int n = tid / 3, c = tid % 3;
    int m = b * NNODE + n;
    vel[n][c] = (x[(size_t)m * 3 + c] - x0[(size_t)m * 3 + c]) * nmask[m];
  }
  __syncthreads();
  if (tid < 4) {
    float s = 0.f;
    if (tid < 3) { for (int n = 0; n < NNODE; n++) s += vel[n][tid]; }
    else         { for (int n = 0; n < NNODE; n++) s += nmask[b * NNODE + n]; }
    sums[tid] = s;
  }
  __syncthreads();
  if (tid < NNODE * 3) {
    int n = tid / 3, c = tid % 3;
    int m = b * NNODE + n;
    float v = (vel[n][c] - sums[c] / sums[3]) * nmask[m];
    out[(size_t)m * 9 + c] = v;
  }
  for (int idx = tid; idx < NNODE * 6; idx += 256) {
    int n = idx / 6, c = idx % 6;
    int m = b * NNODE + n;
    float accv = b_out[c];
    const float* hr = h + (size_t)m * 256;
    for (int k = 0; k < 256; k++) accv += hr[k] * W_out[(size_t)k * 7 + c];
    out[(size_t)m * 9 + 3 + c] = accv * nmask[m];
  }
}

extern "C" void kernel_launch(void* const* d_in, const int* in_sizes, int n_in,
                              void* d_out, int out_size, void* d_ws, size_t ws_size,
                              hipStream_t stream) {
  const float* t       = (const float*)d_in[0];
  const float* xh      = (const float*)d_in[1];
  const float* nmask   = (const float*)d_in[2];
  const float* emask   = (const float*)d_in[3];
  const float* rep     = (const float*)d_in[4];
  const float* W_embed = (const float*)d_in[5];
  const float* b_embed = (const float*)d_in[6];
  const float* W_rep   = (const float*)d_in[7];
  const float* b_rep   = (const float*)d_in[8];
  const float* We1     = (const float*)d_in[9];
  const float* be1     = (const float*)d_in[10];
  const float* We2     = (const float*)d_in[11];
  const float* be2     = (const float*)d_in[12];
  const float* Wn1     = (const float*)d_in[13];
  const float* bn1     = (const float*)d_in[14];
  const float* Wn2     = (const float*)d_in[15];
  const float* bn2     = (const float*)d_in[16];
  const float* Wc1     = (const float*)d_in[17];
  const float* bc1     = (const float*)d_in[18];
  const float* Wc2     = (const float*)d_in[19];
  const float* bc2     = (const float*)d_in[20];
  const float* Wc3     = (const float*)d_in[21];
  const float* W_out   = (const float*)d_in[22];
  const float* b_out   = (const float*)d_in[23];

  char* p = (char*)d_ws;
  auto alloc = [&](size_t bytes) { char* r = p; p += (bytes + 255) & ~(size_t)255; return r; };
  bf16_t* We1T  = (bf16_t*)alloc((size_t)8 * 256 * 520 * 2);   // 2.13 MB
  bf16_t* Wc1T  = (bf16_t*)alloc((size_t)4 * 256 * 520 * 2);   // 1.07 MB
  bf16_t* We2T  = (bf16_t*)alloc((size_t)8 * 256 * 256 * 2);   // 1.05 MB
  bf16_t* Wc2T  = (bf16_t*)alloc((size_t)4 * 256 * 256 * 2);   // 0.52 MB
  bf16_t* Wn1T  = (bf16_t*)alloc((size_t)8 * 256 * 512 * 2);   // 2.10 MB
  bf16_t* Wn2T  = (bf16_t*)alloc((size_t)8 * 256 * 256 * 2);   // 1.05 MB
  float*  h_f32 = (float*) alloc((size_t)NODES * 256 * 4);     // 2.88 MB
  bf16_t* cat1  = (bf16_t*)alloc((size_t)NODES * 512 * 2);     // 2.88 MB
  bf16_t* t1    = (bf16_t*)alloc((size_t)NODES * 256 * 2);     // 1.44 MB
  float*  PQ    = (float*) alloc((size_t)NODES * 512 * 4);     // 5.77 MB
  float*  x0buf = (float*) alloc((size_t)NODES * 3 * 4);
  float*  xA    = (float*) alloc((size_t)NODES * 3 * 4);
  float*  xB    = (float*) alloc((size_t)NODES * 3 * 4);
  float*  rproj = (float*) alloc((size_t)BSZ * 256 * 4);
  // total ~21 MB (<= 24.9 MB established safe in r2)

  dim3 tb(32, 8);
  transpose_wb<<<dim3(8, 17, 8), tb, 0, stream>>>(We1, We1T, 514, 520);
  transpose_wb<<<dim3(8, 17, 4), tb, 0, stream>>>(Wc1, Wc1T, 514, 520);
  transpose_wb<<<dim3(8,  8, 8), tb, 0, stream>>>(We2, We2T, 256, 256);
  transpose_wb<<<dim3(8,  8, 4), tb, 0, stream>>>(Wc2, Wc2T, 256, 256);
  transpose_wb<<<dim3(8, 16, 8), tb, 0, stream>>>(Wn1, Wn1T, 512, 512);
  transpose_wb<<<dim3(8,  8, 8), tb, 0, stream>>>(Wn2, Wn2T, 256, 256);

  repproj_kernel<<<BSZ, 256, 0, stream>>>(rep, W_rep, b_rep, rproj);
  embed_kernel<<<NODES, 256, 0, stream>>>(xh, t, nmask, W_embed, b_embed, rproj,
                                          h_f32, cat1, x0buf, xA);

  float* xcur = xA;
  for (int l = 0; l < 4; l++) {
    float* xnext = (l & 1) ? xA : xB;
    for (int s = 0; s < 2; s++) {
      int k = 2 * l + s;
      size_t oWe1 = (size_t)k * 514 * 256, obe1 = (size_t)k * 256;
      size_t oWe2 = (size_t)k * 256 * 256, obe2 = (size_t)k * 256;
      size_t obn1 = (size_t)k * 256, obn2 = (size_t)k * 256;
      gemm_node<0><<<dim3(4, 44, 2), 256, 0, stream>>>(
          cat1, 512, We1T + (size_t)k * 256 * 520, 520, nullptr, 0, 256,
          PQ, nullptr, nullptr, nullptr, nullptr, nullptr);
      edge_kernel<0><<<NODES, 256, 0, stream>>>(
          PQ, We1, oWe1, be1, obe1, We2T, oWe2, be2, obe2, Wc3, 0,
          xcur, x0buf, emask, nmask, cat1, nullptr);
      gemm_node<1><<<dim3(4, 44, 1), 256, 0, stream>>>(
          cat1, 512, Wn1T + (size_t)k * 256 * 512, 512, bn1, obn1, 512,
          nullptr, t1, nullptr, nullptr, nullptr, nullptr);
      gemm_node<2><<<dim3(4, 44, 1), 256, 0, stream>>>(
          t1, 256, Wn2T + (size_t)k * 256 * 256, 256, bn2, obn2, 256,
          nullptr, nullptr, h_f32, h_f32, cat1, nmask);
    }
    size_t oWc1 = (size_t)l * 514 * 256, obc1 = (size_t)l * 256;
    size_t oWc2 = (size_t)l * 256 * 256, obc2 = (size_t)l * 256;
    size_t oc3  = (size_t)l * 256;
    gemm_node<0><<<dim3(4, 44, 2), 256, 0, stream>>>(
        cat1, 512, Wc1T + (size_t)l * 256 * 520, 520, nullptr, 0, 256,
        PQ, nullptr, nullptr, nullptr, nullptr, nullptr);
    edge_kernel<1><<<NODES, 256, 0, stream>>>(
        PQ, Wc1, oWc1, bc1, obc1, Wc2T, oWc2, bc2, obc2, Wc3, oc3,
        xcur, x0buf, emask, nmask, nullptr, xnext);
    xcur = xnext;
  }

  out_kernel<<<BSZ, 256, 0, stream>>>(h_f32, xcur, x0buf, nmask, W_out, b_out,
                                      (float*)d_out);
}

// Round 12
// 1232.762 us; speedup vs baseline: 9.6630x; 1.2833x over previous
//
#include <hip/hip_runtime.h>

typedef __bf16 bf16_t;
typedef __bf16 bf16x8 __attribute__((ext_vector_type(8)));
typedef float  f32x4  __attribute__((ext_vector_type(4)));

#define BSZ 64
#define NNODE 44
#define NODES (BSZ*NNODE)      /* 2816 */

__device__ __forceinline__ float  bf2f(bf16_t v){ return (float)v; }
__device__ __forceinline__ bf16_t f2bf(float v){ return (bf16_t)v; }
__device__ __forceinline__ float  silu_f(float v){ return v / (1.0f + __expf(-v)); }

// ---------------- batched transpose + f32->bf16: src (G,R,256) -> dst (G,256,ldo)
// dst[g][n][r] = src[g][r][n]
__global__ void transpose_wb(const float* __restrict__ src, bf16_t* __restrict__ dst,
                             int R, int ldo) {
  __shared__ bf16_t tile[32][33];
  int g = blockIdx.z;
  src += (size_t)g * R * 256;
  dst += (size_t)g * 256 * ldo;
  int n0 = blockIdx.x * 32, r0 = blockIdx.y * 32;
  int tx = threadIdx.x, ty = threadIdx.y;   // 32 x 8
  for (int p = 0; p < 32; p += 8) {
    int r = r0 + ty + p;
    if (r < R) tile[ty + p][tx] = f2bf(src[(size_t)r * 256 + n0 + tx]);
  }
  __syncthreads();
  for (int p = 0; p < 32; p += 8) {
    int r = r0 + tx;
    if (r < R) dst[(size_t)(n0 + ty + p) * ldo + r] = tile[tx][ty + p];
  }
}

// ---------------- rproj[b][c] = rep[b]@W_rep[:,c] + b_rep[c]
__global__ __launch_bounds__(256)
void repproj_kernel(const float* __restrict__ rep, const float* __restrict__ W_rep,
                    const float* __restrict__ b_rep, float* __restrict__ out) {
  int b = blockIdx.x, c = threadIdx.x;
  float acc = b_rep[c];
  const float* r = rep + (size_t)b * 512;
  for (int k = 0; k < 512; k++) acc += r[k] * W_rep[(size_t)k * 256 + c];
  out[(size_t)b * 256 + c] = acc;
}

// ---------------- embedding; writes h_f32, cat1[:, :256], x0, xA
__global__ __launch_bounds__(256)
void embed_kernel(const float* __restrict__ xh, const float* __restrict__ t,
                  const float* __restrict__ nmask,
                  const float* __restrict__ W_embed, const float* __restrict__ b_embed,
                  const float* __restrict__ repproj,
                  float* __restrict__ h_f32, bf16_t* __restrict__ cat1,
                  float* __restrict__ x0, float* __restrict__ x) {
  int m = blockIdx.x;
  int b = m / NNODE;
  int c = threadIdx.x;
  float nm = nmask[m];
  float acc = b_embed[c] + repproj[(size_t)b * 256 + c];
  for (int kk = 0; kk < 6; kk++)
    acc += xh[(size_t)m * 9 + 3 + kk] * nm * W_embed[(size_t)kk * 256 + c];
  acc += t[b] * W_embed[6 * 256 + c];
  h_f32[(size_t)m * 256 + c] = acc;
  cat1 [(size_t)m * 512 + c] = f2bf(acc);
  if (c < 3) {
    float xv = xh[(size_t)m * 9 + c] * nm;
    x0[(size_t)m * 3 + c] = xv;
    x [(size_t)m * 3 + c] = xv;
  }
}

// ---------------- node GEMM, BM=64 BN=64, 4 waves of 32x32. ZERO LDS:
// A (bf16 row-major) and BT (bf16 n-major [n][ldbt]) fragments direct from global.
// MODE 0: PQ(f32) at [row*512 + z*256 + col] = A@W
// MODE 1: outB = silu(A@W + bias)            (bf16)
// MODE 2: h = (hold + A@W + bias)*nmask -> h_f32(hnew), cat1[:, :256](catb)
template<int MODE>
__global__ __launch_bounds__(256)
void gemm_node(const bf16_t* __restrict__ A, int lda,
               const bf16_t* __restrict__ BT, int ldbt,
               const float* __restrict__ bias, size_t ob, int K,
               float* __restrict__ outPQ,
               bf16_t* __restrict__ outB,
               const float* __restrict__ hold,
               float* __restrict__ hnew,
               bf16_t* __restrict__ catb,
               const float* __restrict__ nmask) {
  int tid = threadIdx.x;
  int m0 = blockIdx.y * 64, n0 = blockIdx.x * 64;
  int kof = (MODE == 0) ? (int)blockIdx.z * 256 : 0;
  int w = tid >> 6, lane = tid & 63, q = lane >> 4, lr = lane & 15;
  int wm = w & 1, wn = w >> 1;
  f32x4 acc[2][2];
  for (int a = 0; a < 2; a++) for (int bb = 0; bb < 2; bb++)
    for (int rr = 0; rr < 4; rr++) acc[a][bb][rr] = 0.0f;
  const bf16_t* Arow0 = A  + (size_t)(m0 + wm * 32 + lr) * lda;
  const bf16_t* Brow0 = BT + (size_t)(n0 + wn * 32 + lr) * ldbt + kof;
  for (int k0 = 0; k0 < K; k0 += 32) {
    bf16x8 af[2], bfr[2];
    for (int mt = 0; mt < 2; mt++)
      af[mt]  = *(const bf16x8*)(Arow0 + (size_t)mt * 16 * lda + k0 + q * 8);
    for (int nt = 0; nt < 2; nt++)
      bfr[nt] = *(const bf16x8*)(Brow0 + (size_t)nt * 16 * ldbt + k0 + q * 8);
    for (int mt = 0; mt < 2; mt++)
      for (int nt = 0; nt < 2; nt++)
        acc[mt][nt] = __builtin_amdgcn_mfma_f32_16x16x32_bf16(af[mt], bfr[nt], acc[mt][nt], 0, 0, 0);
  }
  for (int mt = 0; mt < 2; mt++)
    for (int nt = 0; nt < 2; nt++) {
      int col = n0 + wn * 32 + nt * 16 + lr;
      for (int rr = 0; rr < 4; rr++) {
        int row = m0 + wm * 32 + mt * 16 + q * 4 + rr;
        float v = acc[mt][nt][rr];
        if constexpr (MODE == 0) {
          outPQ[(size_t)row * 512 + (size_t)blockIdx.z * 256 + col] = v;
        } else if constexpr (MODE == 1) {
          v = silu_f(v + bias[ob + col]);
          outB[(size_t)row * 256 + col] = f2bf(v);
        } else {
          v = v + bias[ob + col] + hold[(size_t)row * 256 + col];
          v *= nmask[row];
          hnew[(size_t)row * 256 + col] = v;
          catb[(size_t)row * 512 + col] = f2bf(v);
        }
      }
    }
}

// ---------------- fused edge kernel: one workgroup per (b,i).
// Distances precomputed per-j into LDS (ddL) — not per (j,n).
// E1 = silu((P_i+be1) + Q_j + d*w512 + d0*w513) in LDS (48x256 over j),
// E2pre = E1 @ We2 + b2 via MFMA; B fragments DIRECT from bf16 W2T (L2-resident).
// COORD=0: agg -> cat1[:, 256:]; COORD=1: phi -> xnext = (xcur + sum/100)*nmask.
template<int COORD>
__global__ __launch_bounds__(256)
void edge_kernel(const float* __restrict__ PQ,
                 const float* __restrict__ We1raw, size_t oW1,  // f32 [514][256] slice
                 const float* __restrict__ be1,   size_t ob1,
                 const bf16_t* __restrict__ W2T,  size_t oW2,   // bf16 [256 n][256 k] slice
                 const float* __restrict__ b2,    size_t ob2,
                 const float* __restrict__ wc3,   size_t oc3,
                 const float* __restrict__ xcur,
                 const float* __restrict__ x0g,
                 const float* __restrict__ emask,
                 const float* __restrict__ nmask,
                 bf16_t* __restrict__ aggout,
                 float* __restrict__ xnext) {
  __shared__ __align__(16) bf16_t Ae[48][264];
  __shared__ float  xjL[48][3], x0jL[48][3];
  __shared__ float2 ddL[48];
  __shared__ float  emLDS[48];
  __shared__ float  phiLDS[4][48];
  int ni = blockIdx.x;
  int b = ni / NNODE;
  int i = ni % NNODE;
  size_t e0 = (size_t)ni * NNODE;
  int tid = threadIdx.x;
  if (tid < NNODE) {
    for (int c = 0; c < 3; c++) {
      xjL [tid][c] = xcur[(size_t)(b * NNODE + tid) * 3 + c];
      x0jL[tid][c] = x0g [(size_t)(b * NNODE + tid) * 3 + c];
    }
  }
  if (tid < 48) emLDS[tid] = (tid < NNODE) ? emask[e0 + tid] : 0.f;
  __syncthreads();
  // per-j distances, computed once per block (not per channel)
  if (tid < NNODE) {
    float dx = xjL[i][0] - xjL[tid][0];
    float dy = xjL[i][1] - xjL[tid][1];
    float dz = xjL[i][2] - xjL[tid][2];
    float dd = dx * dx + dy * dy + dz * dz;
    float ex = x0jL[i][0] - x0jL[tid][0];
    float ey = x0jL[i][1] - x0jL[tid][1];
    float ez = x0jL[i][2] - x0jL[tid][2];
    float dd0 = ex * ex + ey * ey + ez * ez;
    ddL[tid] = make_float2(dd, dd0);
  }
  __syncthreads();
  // ---- A formation (thread == output channel n)
  {
    int n = tid;
    float pi_b = PQ[(size_t)ni * 512 + n] + be1[ob1 + n];
    float w512 = We1raw[oW1 + 512 * 256 + n];
    float w513 = We1raw[oW1 + 513 * 256 + n];
    const float* qptr = PQ + (size_t)(b * NNODE) * 512 + 256 + n;
    #pragma unroll 4
    for (int j = 0; j < NNODE; j++) {
      float2 dd = ddL[j];
      float v = silu_f(pi_b + qptr[(size_t)j * 512] + dd.x * w512 + dd.y * w513);
      Ae[j][n] = f2bf(v);
    }
    for (int j = NNODE; j < 48; j++) Ae[j][n] = (bf16_t)0.f;
  }
  __syncthreads();
  int w = tid >> 6, lane = tid & 63, q = lane >> 4, lr = lane & 15;
  f32x4 acc[3][4];
  for (int mt = 0; mt < 3; mt++) for (int nt = 0; nt < 4; nt++)
    for (int rr = 0; rr < 4; rr++) acc[mt][nt][rr] = 0.0f;
  const bf16_t* Bbase = W2T + oW2 + (size_t)(w * 64 + lr) * 256;
  // ---- K loop: A frags from LDS, B frags direct from global (L2-resident)
  #pragma unroll
  for (int kk = 0; kk < 256; kk += 32) {
    bf16x8 af[3], bfr[4];
    for (int mt = 0; mt < 3; mt++)
      af[mt]  = *(const bf16x8*)(&Ae[mt * 16 + lr][kk + q * 8]);
    for (int nt = 0; nt < 4; nt++)
      bfr[nt] = *(const bf16x8*)(Bbase + (size_t)nt * 16 * 256 + kk + q * 8);
    for (int mt = 0; mt < 3; mt++)
      for (int nt = 0; nt < 4; nt++)
        acc[mt][nt] = __builtin_amdgcn_mfma_f32_16x16x32_bf16(af[mt], bfr[nt], acc[mt][nt], 0, 0, 0);
  }
  // ---- epilogue
  if constexpr (!COORD) {
    for (int nt = 0; nt < 4; nt++) {
      int col = w * 64 + nt * 16 + lr;
      float bcol = b2[ob2 + col];
      float s = 0.f;
      for (int mt = 0; mt < 3; mt++)
        for (int rr = 0; rr < 4; rr++) {
          int row = mt * 16 + q * 4 + rr;
          s += silu_f(acc[mt][nt][rr] + bcol) * emLDS[row];
        }
      s += __shfl_xor(s, 16, 64);
      s += __shfl_xor(s, 32, 64);
      if (q == 0) aggout[(size_t)ni * 512 + 256 + col] = f2bf(s * 0.01f);
    }
  } else {
    for (int mt = 0; mt < 3; mt++) {
      float rs[4] = {0.f, 0.f, 0.f, 0.f};
      for (int nt = 0; nt < 4; nt++) {
        int col = w * 64 + nt * 16 + lr;
        float bcol = b2[ob2 + col];
        float wc   = wc3[oc3 + col];
        for (int rr = 0; rr < 4; rr++)
          rs[rr] += silu_f(acc[mt][nt][rr] + bcol) * wc;
      }
      for (int off = 1; off <= 8; off <<= 1)
        for (int rr = 0; rr < 4; rr++) rs[rr] += __shfl_xor(rs[rr], off, 64);
      if (lr == 0)
        for (int rr = 0; rr < 4; rr++)
          phiLDS[w][mt * 16 + q * 4 + rr] = rs[rr];
    }
    __syncthreads();
    if (tid < 64) {
      int j = lane;
      float tx = 0.f, ty = 0.f, tz = 0.f;
      if (j < NNODE) {
        float ph = 0.f;
        for (int ww = 0; ww < 4; ww++) ph += phiLDS[ww][j];
        ph *= emLDS[j];
        float dx = xjL[i][0] - xjL[j][0];
        float dy = xjL[i][1] - xjL[j][1];
        float dz = xjL[i][2] - xjL[j][2];
        float dd = dx * dx + dy * dy + dz * dz;
        float rinv = 1.0f / sqrtf(dd + 1e-8f);
        tx = ph * dx * rinv;
        ty = ph * dy * rinv;
        tz = ph * dz * rinv;
      }
      for (int off = 1; off <= 32; off <<= 1) {
        tx += __shfl_xor(tx, off, 64);
        ty += __shfl_xor(ty, off, 64);
        tz += __shfl_xor(tz, off, 64);
      }
      if (lane == 0) {
        float nm = nmask[ni];
        xnext[(size_t)ni * 3 + 0] = (xjL[i][0] + tx * 0.01f) * nm;
        xnext[(size_t)ni * 3 + 1] = (xjL[i][1] + ty * 0.01f) * nm;
        xnext[(size_t)ni * 3 + 2] = (xjL[i][2] + tz * 0.01f) * nm;
      }
    }
  }
}

// ---------------- output: vel (mean-subtracted) + h_final -> FLOAT32 out
__global__ __launch_bounds__(256)
void out_kernel(const float* __restrict__ h, const float* __restrict__ x,
                const float* __restrict__ x0, const float* __restrict__ nmask,
                const float* __restrict__ W_out, const float* __restrict__ b_out,
                float* __restrict__ out) {
  __shared__ float vel[NNODE][3];
  __shared__ float sums[4];
  int b = blockIdx.x, tid = threadIdx.x;
  if (tid < NNODE * 3) {
    int n = tid / 3, c = tid % 3;
    int m = b * NNODE + n;
    vel[n][c] = (x[(size_t)m * 3 + c] - x0[(size_t)m * 3 + c]) * nmask[m];
  }
  __syncthreads();
  if (tid < 4) {
    float s = 0.f;
    if (tid < 3) { for (int n = 0; n < NNODE; n++) s += vel[n][tid]; }
    else         { for (int n = 0; n < NNODE; n++) s += nmask[b * NNODE + n]; }
    sums[tid] = s;
  }
  __syncthreads();
  if (tid < NNODE * 3) {
    int n = tid / 3, c = tid % 3;
    int m = b * NNODE + n;
    float v = (vel[n][c] - sums[c] / sums[3]) * nmask[m];
    out[(size_t)m * 9 + c] = v;
  }
  for (int idx = tid; idx < NNODE * 6; idx += 256) {
    int n = idx / 6, c = idx % 6;
    int m = b * NNODE + n;
    float accv = b_out[c];
    const float* hr = h + (size_t)m * 256;
    for (int k = 0; k < 256; k++) accv += hr[k] * W_out[(size_t)k * 7 + c];
    out[(size_t)m * 9 + 3 + c] = accv * nmask[m];
  }
}

extern "C" void kernel_launch(void* const* d_in, const int* in_sizes, int n_in,
                              void* d_out, int out_size, void* d_ws, size_t ws_size,
                              hipStream_t stream) {
  const float* t       = (const float*)d_in[0];
  const float* xh      = (const float*)d_in[1];
  const float* nmask   = (const float*)d_in[2];
  const float* emask   = (const float*)d_in[3];
  const float* rep     = (const float*)d_in[4];
  const float* W_embed = (const float*)d_in[5];
  const float* b_embed = (const float*)d_in[6];
  const float* W_rep   = (const float*)d_in[7];
  const float* b_rep   = (const float*)d_in[8];
  const float* We1     = (const float*)d_in[9];
  const float* be1     = (const float*)d_in[10];
  const float* We2     = (const float*)d_in[11];
  const float* be2     = (const float*)d_in[12];
  const float* Wn1     = (const float*)d_in[13];
  const float* bn1     = (const float*)d_in[14];
  const float* Wn2     = (const float*)d_in[15];
  const float* bn2     = (const float*)d_in[16];
  const float* Wc1     = (const float*)d_in[17];
  const float* bc1     = (const float*)d_in[18];
  const float* Wc2     = (const float*)d_in[19];
  const float* bc2     = (const float*)d_in[20];
  const float* Wc3     = (const float*)d_in[21];
  const float* W_out   = (const float*)d_in[22];
  const float* b_out   = (const float*)d_in[23];

  char* p = (char*)d_ws;
  auto alloc = [&](size_t bytes) { char* r = p; p += (bytes + 255) & ~(size_t)255; return r; };
  bf16_t* We1T  = (bf16_t*)alloc((size_t)8 * 256 * 520 * 2);
  bf16_t* Wc1T  = (bf16_t*)alloc((size_t)4 * 256 * 520 * 2);
  bf16_t* We2T  = (bf16_t*)alloc((size_t)8 * 256 * 256 * 2);
  bf16_t* Wc2T  = (bf16_t*)alloc((size_t)4 * 256 * 256 * 2);
  bf16_t* Wn1T  = (bf16_t*)alloc((size_t)8 * 256 * 512 * 2);
  bf16_t* Wn2T  = (bf16_t*)alloc((size_t)8 * 256 * 256 * 2);
  float*  h_f32 = (float*) alloc((size_t)NODES * 256 * 4);
  bf16_t* cat1  = (bf16_t*)alloc((size_t)NODES * 512 * 2);
  bf16_t* t1    = (bf16_t*)alloc((size_t)NODES * 256 * 2);
  float*  PQ    = (float*) alloc((size_t)NODES * 512 * 4);
  float*  x0buf = (float*) alloc((size_t)NODES * 3 * 4);
  float*  xA    = (float*) alloc((size_t)NODES * 3 * 4);
  float*  xB    = (float*) alloc((size_t)NODES * 3 * 4);
  float*  rproj = (float*) alloc((size_t)BSZ * 256 * 4);

  dim3 tb(32, 8);
  transpose_wb<<<dim3(8, 17, 8), tb, 0, stream>>>(We1, We1T, 514, 520);
  transpose_wb<<<dim3(8, 17, 4), tb, 0, stream>>>(Wc1, Wc1T, 514, 520);
  transpose_wb<<<dim3(8,  8, 8), tb, 0, stream>>>(We2, We2T, 256, 256);
  transpose_wb<<<dim3(8,  8, 4), tb, 0, stream>>>(Wc2, Wc2T, 256, 256);
  transpose_wb<<<dim3(8, 16, 8), tb, 0, stream>>>(Wn1, Wn1T, 512, 512);
  transpose_wb<<<dim3(8,  8, 8), tb, 0, stream>>>(Wn2, Wn2T, 256, 256);

  repproj_kernel<<<BSZ, 256, 0, stream>>>(rep, W_rep, b_rep, rproj);
  embed_kernel<<<NODES, 256, 0, stream>>>(xh, t, nmask, W_embed, b_embed, rproj,
                                          h_f32, cat1, x0buf, xA);

  float* xcur = xA;
  for (int l = 0; l < 4; l++) {
    float* xnext = (l & 1) ? xA : xB;
    for (int s = 0; s < 2; s++) {
      int k = 2 * l + s;
      size_t oWe1 = (size_t)k * 514 * 256, obe1 = (size_t)k * 256;
      size_t oWe2 = (size_t)k * 256 * 256, obe2 = (size_t)k * 256;
      size_t obn1 = (size_t)k * 256, obn2 = (size_t)k * 256;
      gemm_node<0><<<dim3(4, 44, 2), 256, 0, stream>>>(
          cat1, 512, We1T + (size_t)k * 256 * 520, 520, nullptr, 0, 256,
          PQ, nullptr, nullptr, nullptr, nullptr, nullptr);
      edge_kernel<0><<<NODES, 256, 0, stream>>>(
          PQ, We1, oWe1, be1, obe1, We2T, oWe2, be2, obe2, Wc3, 0,
          xcur, x0buf, emask, nmask, cat1, nullptr);
      gemm_node<1><<<dim3(4, 44, 1), 256, 0, stream>>>(
          cat1, 512, Wn1T + (size_t)k * 256 * 512, 512, bn1, obn1, 512,
          nullptr, t1, nullptr, nullptr, nullptr, nullptr);
      gemm_node<2><<<dim3(4, 44, 1), 256, 0, stream>>>(
          t1, 256, Wn2T + (size_t)k * 256 * 256, 256, bn2, obn2, 256,
          nullptr, nullptr, h_f32, h_f32, cat1, nmask);
    }
    size_t oWc1 = (size_t)l * 514 * 256, obc1 = (size_t)l * 256;
    size_t oWc2 = (size_t)l * 256 * 256, obc2 = (size_t)l * 256;
    size_t oc3  = (size_t)l * 256;
    gemm_node<0><<<dim3(4, 44, 2), 256, 0, stream>>>(
        cat1, 512, Wc1T + (size_t)l * 256 * 520, 520, nullptr, 0, 256,
        PQ, nullptr, nullptr, nullptr, nullptr, nullptr);
    edge_kernel<1><<<NODES, 256, 0, stream>>>(
        PQ, Wc1, oWc1, bc1, obc1, Wc2T, oWc2, bc2, obc2, Wc3, oc3,
        xcur, x0buf, emask, nmask, nullptr, xnext);
    xcur = xnext;
  }

  out_kernel<<<BSZ, 256, 0, stream>>>(h_f32, xcur, x0buf, nmask, W_out, b_out,
                                      (float*)d_out);
}